// Round 1
// baseline (138.015 us; speedup 1.0000x reference)
//
#include <hip/hip_runtime.h>

#define WI 512
#define HI 512
#define WO 2048
#define HO 2048
#define NIMG 8
#define CCH 3
#define EPS 1e-8f
#define PLANE (HI * WI)

#define TPB  512      // threads per block (8 waves)
#define SEG  1024     // output px per block (half row)
#define PXT  2        // consecutive px per thread
#define CAP  520      // texel slots per image: 4 zero front-pad + 512 + 4 zero tail-pad

// ===========================================================================
// v9: single-barrier restructure + front-to-back compositing.
//  - per-image uniform state computed once (tid<8) into LDS, ONE barrier
//  - 4 x 128-thread groups stage all images (texel-major (c0,c1,c2) layout,
//    zeroed 4-texel pads) with no inter-image barriers, ONE barrier, then an
//    unbroken blend phase. Blend reads texel pair (k,k+1) from one base ->
//    ds_read2-mergeable; pad trick makes the pair index always safe.
//  - front-to-back with transmittance T: wave-uniform break when T==0
//    (m==1 is exact in interiors), per-segment topmost-full-cover image
//    (fcbits) statically skips bg reads and staging of hidden images.
//  - XCD-chunk block swizzle for src-row L2 locality (4096 = 8*512).
// ===========================================================================
__launch_bounds__(TPB)
__global__ void diffcomp_v9(const float* __restrict__ src,
                            const float* __restrict__ bg,
                            const float* __restrict__ coor,
                            float* __restrict__ out) {
    __shared__ __align__(16) float cs[NIMG][CAP * CCH];
    __shared__ float4 prm[NIMG];   // (a, tx, b, ty)
    __shared__ float4 stA[NIMG];   // (my, t0a_f, lim_f, R_f)   R_f==0 -> skip image
    __shared__ float4 stB[NIMG];   // (wy0, wy1, y0o_f, y1o_f)
    __shared__ __align__(8) unsigned char fcB[NIMG];

    const int tid = threadIdx.x;
    const int b0  = blockIdx.x;
    const int b   = ((b0 & 7) << 9) | (b0 >> 3);   // bijective XCD-chunk swizzle
    const int row = b >> 1;
    const int wo0 = (b & 1) << 10;

    const float ys = (2.0f * (float)row + 1.0f) / (float)HO - 1.0f;

    if (tid < NIMG) {
        const float cx  = coor[tid * 4 + 0];
        const float cy  = coor[tid * 4 + 1];
        const float cw  = coor[tid * 4 + 2];
        const float chh = coor[tid * 4 + 3];
        const float x = (1.0f / (1.0f + expf(-cx))) * (float)WO;
        const float y = (1.0f / (1.0f + expf(-cy))) * (float)HO;
        const float w = (1.0f / (1.0f + expf(-cw))) * (float)WO;
        const float h = (1.0f / (1.0f + expf(-chh))) * (float)HO;
        const float a  = (float)WO / (w + EPS);
        const float tx = (2.0f / (float)WO) * ((float)WO * 0.5f - x) * a;
        const float bb = (float)HO / (h + EPS);
        const float ty = (2.0f / (float)HO) * ((float)HO * 0.5f - y) * bb;
        prm[tid] = make_float4(a, tx, bb, ty);

        // y state (identical expressions to v8)
        const float gy  = bb * ys + ty;
        const float iy  = ((gy + 1.0f) * (float)HI - 1.0f) * 0.5f;
        const float y0f = floorf(iy);
        const float fy1 = iy - y0f;
        const float fy0 = 1.0f - fy1;
        const float y1f = y0f + 1.0f;
        const float vy0 = (y0f >= 0.0f && y0f < (float)HI) ? 1.0f : 0.0f;
        const float vy1 = (y1f >= 0.0f && y1f < (float)HI) ? 1.0f : 0.0f;
        const float wy0 = fy0 * vy0;
        const float wy1 = fy1 * vy1;
        const float my  = wy0 + wy1;
        const float y0of = fminf(fmaxf(y0f, 0.0f), (float)(HI - 1)) * (float)WI;
        const float y1of = fminf(fmaxf(y1f, 0.0f), (float)(HI - 1)) * (float)WI;

        // x window over the segment (identical to v8)
        const float xsf = (2.0f * (float)wo0 + 1.0f) / (float)WO - 1.0f;
        const float xsl = (2.0f * (float)(wo0 + SEG - 1) + 1.0f) / (float)WO - 1.0f;
        const float ixf = ((a * xsf + tx + 1.0f) * (float)WI - 1.0f) * 0.5f;
        const float ixl = ((a * xsl + tx + 1.0f) * (float)WI - 1.0f) * 0.5f;

        const int valid = (my > 0.0f) && !(ixl <= -1.0f || ixf >= (float)WI);
        const int t0  = (int)fminf(fmaxf(floorf(ixf), 0.0f), (float)(WI - 1));
        const int t1  = (int)fminf(fmaxf(floorf(ixl) + 1.0f, 0.0f), (float)(WI - 1));
        const int t0a = t0 & ~3;
        int R = (t1 - t0a + 4) & ~3;
        if (R > WI - t0a) R = WI - t0a;
        const int lim = t1 - t0a;
        stA[tid] = make_float4(my, (float)t0a, (float)lim, valid ? (float)R : 0.0f);
        stB[tid] = make_float4(wy0, wy1, y0of, y1of);

        // full segment coverage: m == 1 exactly for every px of the segment
        const int fc = valid && (my == 1.0f) && (ixf >= 0.0f) && (ixl < (float)(WI - 1));
        fcB[tid] = fc ? (unsigned char)(1u << tid) : (unsigned char)0;
    }
    __syncthreads();

    // fold the 8 flag bytes into a bitmask; j0 = topmost fully-covering image
    const uint2 fw = *(const uint2*)fcB;
    unsigned fv = fw.x | fw.y;
    fv |= fv >> 16;
    fv |= fv >> 8;
    const unsigned fcbits = fv & 0xFFu;
    const int j0 = fcbits ? (31 - __builtin_clz(fcbits)) : 0;

    const int px0   = wo0 + (tid << 1);
    const int gbase = row * WO + px0;

    // bg is only needed when no image fully covers this segment
    float2 Bg[CCH];
    if (fcbits == 0u) {
#pragma unroll
        for (int c = 0; c < CCH; c++)
            Bg[c] = *(const float2*)&bg[c * (HO * WO) + gbase];
    } else {
#pragma unroll
        for (int c = 0; c < CCH; c++)
            Bg[c] = make_float2(0.0f, 0.0f);
    }

    // ---- staging: group g = tid>>7 loads images {g, g+4}; no inter-image barriers
    const int g  = tid >> 7;
    const int xo = (tid & 127) << 2;
#pragma unroll
    for (int ii = 0; ii < 2; ii++) {
        const int n = g + (ii << 2);
        const float4 S = stA[n];
        const int R = (int)S.w;                 // 0 when invalid
        if (n >= j0 && xo < R) {
            const float4 Sb = stB[n];
            const int t0a = (int)S.y;
            const int y0o = (int)Sb.z;
            const int y1o = (int)Sb.w;
            const float* ib = src + n * (CCH * PLANE) + t0a + xo;
            float4 r0[CCH], r1[CCH];
#pragma unroll
            for (int c = 0; c < CCH; c++) {
                r0[c] = *(const float4*)(ib + c * PLANE + y0o);
                r1[c] = *(const float4*)(ib + c * PLANE + y1o);
            }
            const float wy0 = Sb.x, wy1 = Sb.y;
            float wv[12];
#pragma unroll
            for (int t = 0; t < 4; t++) {
#pragma unroll
                for (int c = 0; c < CCH; c++) {
                    const float a0 = ((const float*)&r0[c])[t];
                    const float a1 = ((const float*)&r1[c])[t];
                    wv[t * CCH + c] = a0 * wy0 + a1 * wy1;
                }
            }
            float* dst = &cs[n][(4 + xo) * CCH];      // texel-major, +4 front pad
            ((float4*)dst)[0] = make_float4(wv[0], wv[1], wv[2],  wv[3]);
            ((float4*)dst)[1] = make_float4(wv[4], wv[5], wv[6],  wv[7]);
            ((float4*)dst)[2] = make_float4(wv[8], wv[9], wv[10], wv[11]);
            const float4 z4 = make_float4(0.0f, 0.0f, 0.0f, 0.0f);
            if (xo == 0) {                            // zero front pad (texels 0..3)
                float4* pz = (float4*)&cs[n][0];
                pz[0] = z4; pz[1] = z4; pz[2] = z4;
            }
            if (xo == R - 4) {                        // zero tail pad (texels R+4..R+7)
                float4* pz = (float4*)&cs[n][(R + 4) * CCH];
                pz[0] = z4; pz[1] = z4; pz[2] = z4;
            }
        }
    }
    __syncthreads();

    // ---- blend: front-to-back with transmittance T, wave-uniform early out
    float xsv[PXT];
#pragma unroll
    for (int p = 0; p < PXT; p++)
        xsv[p] = (2.0f * (float)(px0 + p) + 1.0f) / (float)WO - 1.0f;

    const int pxF = wo0 + ((tid >> 6) << 7);          // wave's first px (128-px span)
    const float xsF = (2.0f * (float)pxF + 1.0f) / (float)WO - 1.0f;
    const float xsL = (2.0f * (float)(pxF + 127) + 1.0f) / (float)WO - 1.0f;

    float C[CCH][PXT];
#pragma unroll
    for (int c = 0; c < CCH; c++) { C[c][0] = 0.0f; C[c][1] = 0.0f; }
    float T[PXT];
    T[0] = 1.0f; T[1] = 1.0f;

#pragma unroll
    for (int n = NIMG - 1; n >= 0; --n) {
        const float4 S = stA[n];
        if (S.w > 0.0f) {                             // uniform branch
            const float4 P = prm[n];
            const float a = P.x, tx = P.y;
            const float gxF = a * xsF + tx;
            const float ixF = ((gxF + 1.0f) * (float)WI - 1.0f) * 0.5f;
            const float gxL = a * xsL + tx;
            const float ixL = ((gxL + 1.0f) * (float)WI - 1.0f) * 0.5f;
            if (!(ixL <= -1.0f || ixF >= (float)WI)) {    // exact wave-level skip
                const float my = S.x, t0af = S.y, limf = S.z;
                const float* ldsn = &cs[n][0];
#pragma unroll
                for (int p = 0; p < PXT; p++) {
                    const float gx  = a * xsv[p] + tx;
                    const float ix  = ((gx + 1.0f) * (float)WI - 1.0f) * 0.5f;
                    const float x0f = floorf(ix);
                    const float fx1 = ix - x0f;
                    const float fx0 = 1.0f - fx1;
                    const float v0  = (x0f >= 0.0f  && x0f < (float)WI) ? 1.0f : 0.0f;
                    const float v1  = (x0f >= -1.0f && x0f < (float)(WI - 1)) ? 1.0f : 0.0f;
                    const float wx0 = fx0 * v0;
                    const float wx1 = fx1 * v1;
                    const float xr  = fminf(fmaxf(x0f - t0af, -1.0f), limf);
                    const int   k   = (int)xr + 4;        // pad-shifted texel slot
                    const float* tp = ldsn + k * CCH;     // reads (k, k+1): mergeable
                    const float m   = my * (wx0 + wx1);
                    const float om  = 1.0f - m;
                    const float wm  = T[p] * m;
                    T[p] *= om;
#pragma unroll
                    for (int c = 0; c < CCH; c++) {
                        const float sc = tp[c] * wx0 + tp[c + CCH] * wx1;
                        C[c][p] += wm * sc;
                    }
                }
            }
        }
        if (!__any(T[0] > 0.0f || T[1] > 0.0f)) break; // everything below is hidden
    }

    if (fcbits == 0u) {
#pragma unroll
        for (int c = 0; c < CCH; c++) {
            C[c][0] += T[0] * Bg[c].x;
            C[c][1] += T[1] * Bg[c].y;
        }
    }
#pragma unroll
    for (int c = 0; c < CCH; c++)
        *(float2*)&out[c * (HO * WO) + gbase] = make_float2(C[c][0], C[c][1]);
}

extern "C" void kernel_launch(void* const* d_in, const int* in_sizes, int n_in,
                              void* d_out, int out_size, void* d_ws, size_t ws_size,
                              hipStream_t stream) {
    const float* src  = (const float*)d_in[0];   // [8,3,512,512]
    const float* bg   = (const float*)d_in[1];   // [1,3,2048,2048]
    const float* coor = (const float*)d_in[2];   // [8,4]
    float* out = (float*)d_out;                  // [1,3,2048,2048]
    (void)d_ws; (void)ws_size;

    hipLaunchKernelGGL(diffcomp_v9, dim3(HO * (WO / SEG)), dim3(TPB), 0, stream,
                       src, bg, coor, out);
}

// Round 2
// 134.856 us; speedup vs baseline: 1.0234x; 1.0234x over previous
//
#include <hip/hip_runtime.h>

#define WI 512
#define HI 512
#define WO 2048
#define HO 2048
#define NIMG 8
#define CCH 3
#define EPS 1e-8f
#define PLANE (HI * WI)

#define TPB  256      // threads per block
#define SEG  1024     // output px per block (half row)
#define PXT  4        // px per thread, strided by TPB
#define CAP  520      // LDS texels per channel slot (512 + float4 slack)

struct SState {       // per-(image,row,segment) uniform state
    float wy0, wy1, my;
    int   t0a, R, lim;
    int   valid;
    int   fc;         // full coverage: m == 1 (exactly) for every px of segment
};

// y/x uniforms for image-param P at row ys, segment [wo0, wo0+SEG).
// valid==0 -> m==0 for every px of the segment (exact skip).
// fc==1    -> m==1 for every px of the segment (exact occlusion).
__device__ __forceinline__ SState calc_state(const float4 P, const float ys,
                                             const int wo0) {
    SState st; st.valid = 0; st.fc = 0; st.wy0 = st.wy1 = st.my = 0.0f;
    st.t0a = 0; st.R = 0; st.lim = 0;
    const float gy  = P.z * ys + P.w;
    const float iy  = ((gy + 1.0f) * (float)HI - 1.0f) * 0.5f;
    const float y0f = floorf(iy);
    const float fy1 = iy - y0f;
    const float fy0 = 1.0f - fy1;
    const float y1f = y0f + 1.0f;
    const float v0  = (y0f >= 0.0f && y0f < (float)HI) ? 1.0f : 0.0f;
    const float v1  = (y1f >= 0.0f && y1f < (float)HI) ? 1.0f : 0.0f;
    st.wy0 = fy0 * v0;
    st.wy1 = fy1 * v1;
    st.my  = st.wy0 + st.wy1;
    if (!(st.my > 0.0f)) return st;

    const float a  = P.x, tx = P.y;
    const float xsf = (2.0f * (float)wo0 + 1.0f) / (float)WO - 1.0f;
    const float xsl = (2.0f * (float)(wo0 + SEG - 1) + 1.0f) / (float)WO - 1.0f;
    const float ixf = ((a * xsf + tx + 1.0f) * (float)WI - 1.0f) * 0.5f;
    const float ixl = ((a * xsl + tx + 1.0f) * (float)WI - 1.0f) * 0.5f;
    if (ixl <= -1.0f || ixf >= (float)WI) return st;    // all wx == 0

    const int t0 = (int)fminf(fmaxf(floorf(ixf), 0.0f), (float)(WI - 1));
    const int t1 = (int)fminf(fmaxf(floorf(ixl) + 1.0f, 0.0f), (float)(WI - 1));
    st.t0a = t0 & ~3;                                   // float4 alignment
    int R = (t1 - st.t0a + 4) & ~3;                     // round up to x4
    if (R > WI - st.t0a) R = WI - st.t0a;               // stay inside the row
    st.R   = R;
    st.lim = t1 - st.t0a;
    st.valid = 1;
    // both y-taps valid (my==1) and both x-taps interior for the whole segment
    st.fc = (st.my == 1.0f) && (ixf >= 0.0f) && (ixl < (float)(WI - 1));
    return st;
}

// ===========================================================================
// v10: v8's measured-best software pipeline, unchanged, plus v9's exact
// occlusion skipping: topmost fully-covering image j0 masks out the staging
// AND blending of all images below it, and replaces the bg read with zeros.
// (m==1 exactly in interiors -> om==0 -> lower layers contribute nothing.)
// ===========================================================================
__launch_bounds__(TPB)
__global__ void diffcomp_v10(const float* __restrict__ src,
                             const float* __restrict__ bg,
                             const float* __restrict__ coor,
                             float* __restrict__ out) {
    __shared__ float  cs[2][CCH][CAP];
    __shared__ float4 prm[NIMG];

    const int tid = threadIdx.x;
    const int b   = blockIdx.x;
    const int row = b >> 1;
    const int wo0 = (b & 1) << 10;

    if (tid < NIMG) {
        const float cx  = coor[tid * 4 + 0];
        const float cy  = coor[tid * 4 + 1];
        const float cw  = coor[tid * 4 + 2];
        const float chh = coor[tid * 4 + 3];
        const float x = (1.0f / (1.0f + expf(-cx))) * (float)WO;
        const float y = (1.0f / (1.0f + expf(-cy))) * (float)HO;
        const float w = (1.0f / (1.0f + expf(-cw))) * (float)WO;
        const float h = (1.0f / (1.0f + expf(-chh))) * (float)HO;
        const float a  = (float)WO / (w + EPS);
        const float tx = (2.0f / (float)WO) * ((float)WO * 0.5f - x) * a;
        const float bb = (float)HO / (h + EPS);
        const float ty = (2.0f / (float)HO) * ((float)HO * 0.5f - y) * bb;
        prm[tid] = make_float4(a, tx, bb, ty);
    }
    __syncthreads();

    const float ys = (2.0f * (float)row + 1.0f) / (float)HO - 1.0f;

    // Coverage + full-coverage masks (uniform across the block).
    unsigned cov = 0u, fcb = 0u;
#pragma unroll
    for (int n = 0; n < NIMG; n++) {
        const SState s = calc_state(prm[n], ys, wo0);
        if (s.valid) cov |= (1u << n);
        if (s.fc)    fcb |= (1u << n);
    }
    // Topmost fully-covering image hides bg and everything below it (exact).
    if (fcb) {
        const int j0 = 31 - __builtin_clz(fcb);
        cov &= ~((1u << j0) - 1u);
    }

    // Per-px xs values (image-independent), hoisted out of the image loop.
    float xsv[PXT];
#pragma unroll
    for (int p = 0; p < PXT; p++) {
        const int wo = wo0 + p * TPB + tid;
        xsv[p] = (2.0f * (float)wo + 1.0f) / (float)WO - 1.0f;
    }

    // Accumulators (strided, lane-consecutive, coalesced).
    const int base = row * WO + wo0 + tid;
    float acc[CCH][PXT];
    if (fcb == 0u) {
#pragma unroll
        for (int c = 0; c < CCH; c++)
#pragma unroll
            for (int p = 0; p < PXT; p++)
                acc[c][p] = bg[c * HO * WO + base + p * TPB];
    } else {
#pragma unroll
        for (int c = 0; c < CCH; c++)
#pragma unroll
            for (int p = 0; p < PXT; p++)
                acc[c][p] = 0.0f;
    }

    if (cov) {
        // ---- register-stage loaders ----
        float4 A0[CCH], A1[CCH], B0[CCH], B1[CCH];
        SState stA, stB;

        auto load_img = [&](int n, SState& st, float4* r0, float4* r1) {
            st = calc_state(prm[n], ys, wo0);
            const int xo = tid << 2;
            if (xo < st.R) {
                const float* ib = src + n * (CCH * PLANE) + st.t0a + xo;
                const float gy  = prm[n].z * ys + prm[n].w;
                const float iy  = ((gy + 1.0f) * (float)HI - 1.0f) * 0.5f;
                const float y0f = floorf(iy);
                const int y0o = (int)fminf(fmaxf(y0f, 0.0f), (float)(HI - 1)) * WI;
                const int y1o = (int)fminf(fmaxf(y0f + 1.0f, 0.0f), (float)(HI - 1)) * WI;
#pragma unroll
                for (int c = 0; c < CCH; c++) {
                    r0[c] = *(const float4*)(ib + c * PLANE + y0o);
                    r1[c] = *(const float4*)(ib + c * PLANE + y1o);
                }
            }
        };

        auto commit_img = [&](int slot, const SState& st,
                              const float4* r0, const float4* r1) {
            const int xo = tid << 2;
            if (xo < st.R) {
#pragma unroll
                for (int c = 0; c < CCH; c++) {
                    float4 rc;
                    rc.x = r0[c].x * st.wy0 + r1[c].x * st.wy1;
                    rc.y = r0[c].y * st.wy0 + r1[c].y * st.wy1;
                    rc.z = r0[c].z * st.wy0 + r1[c].z * st.wy1;
                    rc.w = r0[c].w * st.wy0 + r1[c].w * st.wy1;
                    *(float4*)&cs[slot][c][xo] = rc;
                }
            }
        };

        auto blend_img = [&](int slot, int n, const SState& st) {
            const float a  = prm[n].x;
            const float tx = prm[n].y;
#pragma unroll
            for (int p = 0; p < PXT; p++) {
                const float gx  = a * xsv[p] + tx;
                const float ix  = ((gx + 1.0f) * (float)WI - 1.0f) * 0.5f;
                const float x0f = floorf(ix);
                const float fx1 = ix - x0f;
                const float fx0 = 1.0f - fx1;
                const float x1f = x0f + 1.0f;
                const float v0  = (x0f >= 0.0f && x0f < (float)WI) ? 1.0f : 0.0f;
                const float v1  = (x1f >= 0.0f && x1f < (float)WI) ? 1.0f : 0.0f;
                const float wx0 = fx0 * v0;
                const float wx1 = fx1 * v1;
                int x0r = (int)fminf(fmaxf(x0f, 0.0f), (float)(WI - 1)) - st.t0a;
                int x1r = (int)fminf(fmaxf(x1f, 0.0f), (float)(WI - 1)) - st.t0a;
                x0r = min(max(x0r, 0), st.lim);
                x1r = min(max(x1r, 0), st.lim);
                const float m  = st.my * (wx0 + wx1);
                const float om = 1.0f - m;
#pragma unroll
                for (int c = 0; c < CCH; c++) {
                    const float q0 = cs[slot][c][x0r];
                    const float q1 = cs[slot][c][x1r];
                    const float sc = q0 * wx0 + q1 * wx1;
                    acc[c][p] = acc[c][p] * om + sc * m;
                }
            }
        };

        int cur = (int)__builtin_ctz(cov);
        unsigned rest = cov & (cov - 1u);

        load_img(cur, stA, A0, A1);
        int s = 0;
        while (true) {
            const int nxt = rest ? (int)__builtin_ctz(rest) : -1;
            if (nxt >= 0) load_img(nxt, stB, B0, B1);   // in flight across blend
            commit_img(s, stA, A0, A1);
            __syncthreads();
            blend_img(s, cur, stA);
            if (nxt < 0) break;
            cur = nxt;
            rest &= rest - 1u;
            stA = stB;
#pragma unroll
            for (int c = 0; c < CCH; c++) { A0[c] = B0[c]; A1[c] = B1[c]; }
            s ^= 1;
        }
    }

#pragma unroll
    for (int c = 0; c < CCH; c++)
#pragma unroll
        for (int p = 0; p < PXT; p++)
            out[c * HO * WO + base + p * TPB] = acc[c][p];
}

extern "C" void kernel_launch(void* const* d_in, const int* in_sizes, int n_in,
                              void* d_out, int out_size, void* d_ws, size_t ws_size,
                              hipStream_t stream) {
    const float* src  = (const float*)d_in[0];   // [8,3,512,512]
    const float* bg   = (const float*)d_in[1];   // [1,3,2048,2048]
    const float* coor = (const float*)d_in[2];   // [8,4]
    float* out = (float*)d_out;                  // [1,3,2048,2048]
    (void)d_ws; (void)ws_size;

    hipLaunchKernelGGL(diffcomp_v10, dim3(HO * (WO / SEG)), dim3(TPB), 0, stream,
                       src, bg, coor, out);
}

// Round 3
// 134.144 us; speedup vs baseline: 1.0289x; 1.0053x over previous
//
#include <hip/hip_runtime.h>

#define WI 512
#define HI 512
#define WO 2048
#define HO 2048
#define NIMG 8
#define CCH 3
#define EPS 1e-8f
#define PLANE (HI * WI)

#define TPB  256      // threads per block
#define SEG  1024     // output px per block (half row)
#define PXT  4        // CONSECUTIVE px per thread
#define CAP  520      // texel capacity per LDS slot

// ===========================================================================
// v11: v10's verified pipeline (load->commit->barrier->blend, dbuf slots,
// occlusion cull) with the VALU work cut ~3x:
//  - per-image uniform state computed ONCE (tid<8) into LDS, read back by
//    broadcast; no per-thread calc_state replication.
//  - affine collapse: ix = A2*(px + D) + 255.5 (one add+fma per px); same
//    formula for segment window / wave test / per-px => floor monotonicity
//    proves fast-path indices stay inside the staged window.
//  - wave-uniform interior fast path (my==1 exact => pure replace, no
//    clamps, no v-weights); boundary waves keep full reference math.
//  - texel-major LDS (c fastest): x-taps are +0/+3 dwords from one base ->
//    ds_read2_b32-mergeable; commit float4 stores are bank-conflict-free.
//  - consecutive 4 px/thread: bg/out as float4; XCD-chunk swizzle.
// ===========================================================================
__launch_bounds__(TPB)
__global__ void diffcomp_v11(const float* __restrict__ src,
                             const float* __restrict__ bg,
                             const float* __restrict__ coor,
                             float* __restrict__ out) {
    __shared__ __align__(16) float cs[2][CAP * CCH];   // texel-major
    __shared__ float4 st1[NIMG];   // (my, t0a_f, lim_f, R_f)  R_f==0 -> invalid
    __shared__ float4 st2[NIMG];   // (wy0, wy1, y0o_f, y1o_f)
    __shared__ float4 st3[NIMG];   // (A2, D, fc_f, 0)

    const int tid = threadIdx.x;
    const int b0  = blockIdx.x;
    const int b   = ((b0 & 7) << 9) | (b0 >> 3);       // bijective XCD swizzle
    const int row = b >> 1;
    const int wo0 = (b & 1) << 10;
    const float ys = (2.0f * (float)row + 1.0f) / (float)HO - 1.0f;
    const float HW1 = 0.5f * (float)(WI - 1);

    if (tid < NIMG) {
        const float cx  = coor[tid * 4 + 0];
        const float cy  = coor[tid * 4 + 1];
        const float cw  = coor[tid * 4 + 2];
        const float chh = coor[tid * 4 + 3];
        const float xx = (1.0f / (1.0f + expf(-cx))) * (float)WO;
        const float yy = (1.0f / (1.0f + expf(-cy))) * (float)HO;
        const float w  = (1.0f / (1.0f + expf(-cw))) * (float)WO;
        const float h  = (1.0f / (1.0f + expf(-chh))) * (float)HO;
        const float a  = (float)WO / (w + EPS);
        const float bb = (float)HO / (h + EPS);
        const float ty = (2.0f / (float)HO) * ((float)HO * 0.5f - yy) * bb;

        // y state (reference chain, as v10)
        const float gy  = bb * ys + ty;
        const float iy  = ((gy + 1.0f) * (float)HI - 1.0f) * 0.5f;
        const float y0f = floorf(iy);
        const float fy1 = iy - y0f;
        const float fy0 = 1.0f - fy1;
        const float y1f = y0f + 1.0f;
        const float v0  = (y0f >= 0.0f && y0f < (float)HI) ? 1.0f : 0.0f;
        const float v1  = (y1f >= 0.0f && y1f < (float)HI) ? 1.0f : 0.0f;
        const float wy0 = fy0 * v0;
        const float wy1 = fy1 * v1;
        const float my  = wy0 + wy1;
        const float y0of = fminf(fmaxf(y0f, 0.0f), (float)(HI - 1)) * (float)WI;
        const float y1of = fminf(fmaxf(y1f, 0.0f), (float)(HI - 1)) * (float)WI;

        // x mapping: ix(wo) = A2*(wo + D) + HW1   (analytic collapse)
        const float A2 = a * ((float)WI / (float)WO);
        const float D  = 0.5f - xx;

        float myv = 0.0f, t0af = 0.0f, limf = 0.0f, Rf = 0.0f, fcf = 0.0f;
        if (my > 0.0f) {
            const float ixf = fmaf(A2, (float)wo0 + D, HW1);
            const float ixl = fmaf(A2, (float)(wo0 + SEG - 1) + D, HW1);
            if (!(ixl <= -1.0f || ixf >= (float)WI)) {
                const int t0 = (int)fminf(fmaxf(floorf(ixf), 0.0f), (float)(WI - 1));
                const int t1 = (int)fminf(fmaxf(floorf(ixl) + 1.0f, 0.0f), (float)(WI - 1));
                const int t0a = t0 & ~3;
                int R = (t1 - t0a + 4) & ~3;
                if (R > WI - t0a) R = WI - t0a;
                myv = my; t0af = (float)t0a; limf = (float)(t1 - t0a); Rf = (float)R;
                fcf = (my == 1.0f && ixf >= 0.0f && ixl < (float)(WI - 1)) ? 1.0f : 0.0f;
            }
        }
        st1[tid] = make_float4(myv, t0af, limf, Rf);
        st2[tid] = make_float4(wy0, wy1, y0of, y1of);
        st3[tid] = make_float4(A2, D, fcf, 0.0f);
    }
    __syncthreads();

    // coverage masks from LDS state (broadcast reads, uniform values)
    unsigned cov = 0u, fcb = 0u;
#pragma unroll
    for (int n = 0; n < NIMG; n++) {
        if (st1[n].w > 0.0f) cov |= (1u << n);
        if (st3[n].z > 0.0f) fcb |= (1u << n);
    }
    if (fcb) {
        const int j0 = 31 - __builtin_clz(fcb);
        cov &= ~((1u << j0) - 1u);            // images below j0 are hidden (exact)
    }

    const int px0   = wo0 + (tid << 2);
    const int gbase = row * WO + px0;

    float acc[CCH][PXT];
    if (fcb == 0u) {
#pragma unroll
        for (int c = 0; c < CCH; c++) {
            const float4 bv = *(const float4*)&bg[c * (HO * WO) + gbase];
            acc[c][0] = bv.x; acc[c][1] = bv.y; acc[c][2] = bv.z; acc[c][3] = bv.w;
        }
    } else {
#pragma unroll
        for (int c = 0; c < CCH; c++)
#pragma unroll
            for (int p = 0; p < PXT; p++)
                acc[c][p] = 0.0f;
    }

    if (cov) {
        float4 A0[CCH], A1[CCH], B0[CCH], B1[CCH];
        float4 s1A, s2A, s3A, s1B, s2B, s3B;

        auto load_img = [&](int n, float4& s1, float4& s2, float4& s3,
                            float4* r0, float4* r1) {
            s1 = st1[n]; s2 = st2[n]; s3 = st3[n];
            const int xo = tid << 2;
            if (xo < (int)s1.w) {
                const float* ib = src + n * (CCH * PLANE) + (int)s1.y + xo;
                const int y0o = (int)s2.z;
                const int y1o = (int)s2.w;
#pragma unroll
                for (int c = 0; c < CCH; c++) {
                    r0[c] = *(const float4*)(ib + c * PLANE + y0o);
                    r1[c] = *(const float4*)(ib + c * PLANE + y1o);
                }
            }
        };

        auto commit_img = [&](int slot, const float4 s1, const float4 s2,
                              const float4* r0, const float4* r1) {
            const int xo = tid << 2;
            if (xo < (int)s1.w) {
                const float wy0 = s2.x, wy1 = s2.y;
                float wv[12];
#pragma unroll
                for (int t = 0; t < 4; t++)
#pragma unroll
                    for (int c = 0; c < CCH; c++)
                        wv[t * CCH + c] = ((const float*)&r0[c])[t] * wy0
                                        + ((const float*)&r1[c])[t] * wy1;
                float* dst = &cs[slot][xo * CCH];     // texel-major, 16B aligned
                ((float4*)dst)[0] = make_float4(wv[0], wv[1], wv[2],  wv[3]);
                ((float4*)dst)[1] = make_float4(wv[4], wv[5], wv[6],  wv[7]);
                ((float4*)dst)[2] = make_float4(wv[8], wv[9], wv[10], wv[11]);
            }
        };

        auto blend_img = [&](int slot, const float4 s1, const float4 s3) {
            const float my = s1.x, t0af = s1.y;
            const float A2 = s3.x, D = s3.y;
            const float* ls = &cs[slot][0];
            // wave-uniform span test (monotone fma => bounds cover all lanes/px)
            const int pw0 = wo0 + ((tid >> 6) << 8);
            const float ixF = fmaf(A2, (float)pw0 + D, HW1);
            const float ixL = fmaf(A2, (float)(pw0 + 255) + D, HW1);
            if (ixL <= -1.0f || ixF >= (float)WI) return;   // wave fully outside
            if (ixF >= 0.0f && ixL < (float)(WI - 1)) {
                // interior: both taps valid for every px of this wave
                const float omy = 1.0f - my;
                if (omy == 0.0f) {                          // my==1: pure replace
#pragma unroll
                    for (int p = 0; p < PXT; p++) {
                        const float ix  = fmaf(A2, (float)(px0 + p) + D, HW1);
                        const float x0f = floorf(ix);
                        const float fx1 = ix - x0f;
                        const int   k   = (int)(x0f - t0af);
                        const float* tp = ls + k * CCH;
#pragma unroll
                        for (int c = 0; c < CCH; c++) {
                            const float q0 = tp[c];
                            const float q1 = tp[c + CCH];
                            acc[c][p] = q0 + fx1 * (q1 - q0);
                        }
                    }
                } else {                                    // edge row: uniform m=my
#pragma unroll
                    for (int p = 0; p < PXT; p++) {
                        const float ix  = fmaf(A2, (float)(px0 + p) + D, HW1);
                        const float x0f = floorf(ix);
                        const float fx1 = ix - x0f;
                        const int   k   = (int)(x0f - t0af);
                        const float* tp = ls + k * CCH;
#pragma unroll
                        for (int c = 0; c < CCH; c++) {
                            const float q0 = tp[c];
                            const float q1 = tp[c + CCH];
                            const float sc = q0 + fx1 * (q1 - q0);
                            acc[c][p] = acc[c][p] * omy + my * sc;
                        }
                    }
                }
            } else {
                // boundary wave: full reference math with clamps
                const int lim = (int)s1.z;
                const int t0a = (int)t0af;
#pragma unroll
                for (int p = 0; p < PXT; p++) {
                    const float ix  = fmaf(A2, (float)(px0 + p) + D, HW1);
                    const float x0f = floorf(ix);
                    const float fx1 = ix - x0f;
                    const float fx0 = 1.0f - fx1;
                    const float x1f = x0f + 1.0f;
                    const float v0  = (x0f >= 0.0f && x0f < (float)WI) ? 1.0f : 0.0f;
                    const float v1  = (x1f >= 0.0f && x1f < (float)WI) ? 1.0f : 0.0f;
                    const float wx0 = fx0 * v0;
                    const float wx1 = fx1 * v1;
                    int x0r = (int)fminf(fmaxf(x0f, 0.0f), (float)(WI - 1)) - t0a;
                    int x1r = (int)fminf(fmaxf(x1f, 0.0f), (float)(WI - 1)) - t0a;
                    x0r = min(max(x0r, 0), lim);
                    x1r = min(max(x1r, 0), lim);
                    const float m  = my * (wx0 + wx1);
                    const float om = 1.0f - m;
#pragma unroll
                    for (int c = 0; c < CCH; c++) {
                        const float q0 = ls[x0r * CCH + c];
                        const float q1 = ls[x1r * CCH + c];
                        acc[c][p] = acc[c][p] * om + (q0 * wx0 + q1 * wx1) * m;
                    }
                }
            }
        };

        int cur = (int)__builtin_ctz(cov);
        unsigned rest = cov & (cov - 1u);

        load_img(cur, s1A, s2A, s3A, A0, A1);
        int s = 0;
        while (true) {
            const int nxt = rest ? (int)__builtin_ctz(rest) : -1;
            if (nxt >= 0) load_img(nxt, s1B, s2B, s3B, B0, B1); // in flight
            commit_img(s, s1A, s2A, A0, A1);
            __syncthreads();
            blend_img(s, s1A, s3A);
            if (nxt < 0) break;
            cur = nxt;
            rest &= rest - 1u;
            s1A = s1B; s2A = s2B; s3A = s3B;
#pragma unroll
            for (int c = 0; c < CCH; c++) { A0[c] = B0[c]; A1[c] = B1[c]; }
            s ^= 1;
        }
    }

#pragma unroll
    for (int c = 0; c < CCH; c++)
        *(float4*)&out[c * (HO * WO) + gbase] =
            make_float4(acc[c][0], acc[c][1], acc[c][2], acc[c][3]);
}

extern "C" void kernel_launch(void* const* d_in, const int* in_sizes, int n_in,
                              void* d_out, int out_size, void* d_ws, size_t ws_size,
                              hipStream_t stream) {
    const float* src  = (const float*)d_in[0];   // [8,3,512,512]
    const float* bg   = (const float*)d_in[1];   // [1,3,2048,2048]
    const float* coor = (const float*)d_in[2];   // [8,4]
    float* out = (float*)d_out;                  // [1,3,2048,2048]
    (void)d_ws; (void)ws_size;

    hipLaunchKernelGGL(diffcomp_v11, dim3(HO * (WO / SEG)), dim3(TPB), 0, stream,
                       src, bg, coor, out);
}